// Round 8
// baseline (122.946 us; speedup 1.0000x reference)
//
#include <hip/hip_runtime.h>
#include <hip/hip_bf16.h>
#include <stdint.h>

#define B_ 2
#define N_ 4096
#define C_ 8
#define MAXDET 100
#define SCORE_THR 0.01f
#define NMS_THR 0.5f
#define NEGV -1e30f

typedef unsigned long long u64;

// ---------- helpers ----------
__device__ __forceinline__ unsigned mono_key(float f) {
    unsigned u = __float_as_uint(f);
    return (u & 0x80000000u) ? ~u : (u | 0x80000000u);
}
__device__ __forceinline__ float mono_dec(unsigned m) {
    return (m & 0x80000000u) ? __uint_as_float(m ^ 0x80000000u)
                             : __uint_as_float(~m);
}
// exact predicate: RN32(inter/uni) > 0.5  (uni > 0)
__device__ __forceinline__ bool iou_gt_half(float inter, float uni) {
    return (inter + inter - uni) > uni * 0x1p-25f;
}
// wave-synchronous LDS fence (single-wave producer/consumer, no s_barrier)
__device__ __forceinline__ void wave_fence() {
    asm volatile("s_waitcnt lgkmcnt(0)" ::: "memory");
}

// ---------- 1) mega: sort + top-1024 merge + mask + greedy scan ----------
// One block per (b,c). Stages 2..1024 of the full 4096 bitonic network leave
// quarters sorted desc/asc/desc/asc in m[] (= old sortA output, kept intact
// for the gated fallback). Top-256 of each quarter merges in m2[]; top-192
// boxes + 192x3 cmask live in LDS; wave 0 runs the greedy scan LDS-resident.
__global__ __launch_bounds__(512) void mega_kernel(
    const float* __restrict__ cls_in,
    const float* __restrict__ boxes,
    u64* __restrict__ cand)   // (B*C, 128)
{
    __shared__ u64 m[4096];          // quarter-sorted keys (fallback source)
    __shared__ u64 m2[1024];         // top-1024 merge
    __shared__ float4 sb192[192];
    __shared__ float  sa192[192];
    __shared__ u64 cm[576];          // 192 rows x 3 words
    __shared__ float4 sbx[64];       // fallback only
    __shared__ u64 shJ[64];          // fallback only
    __shared__ int s_fin;

    const int bc = blockIdx.x;
    const int b = bc >> 3, cls = bc & 7;
    const int tid = threadIdx.x;
    const int lane = tid & 63;
    const int wave = tid >> 6;
    const float4* boxes4 = (const float4*)boxes;

    // ---- build keys ----
    for (int i = tid; i < 4096; i += 512) {
        float s = cls_in[((size_t)b * N_ + i) * C_ + cls];
        float f = (s > SCORE_THR) ? s : NEGV;
        m[i] = ((u64)mono_key(f) << 32) | (unsigned)(~i);
    }
    __syncthreads();

    // ---- full-network stages size 2..1024 (quarters sorted alternating) ----
    for (int size = 2; size <= 1024; size <<= 1) {
        for (int stride = size >> 1; stride > 0; stride >>= 1) {
            for (int t = tid; t < 2048; t += 512) {
                int pos = 2 * t - (t & (stride - 1));
                int par = pos + stride;
                bool d = ((pos & size) == 0);
                u64 a = m[pos], bb = m[par];
                if ((a < bb) == d) { m[pos] = bb; m[par] = a; }
            }
            __syncthreads();
        }
    }

    // ---- top-256 of each quarter -> m2 (piecewise desc/asc/desc/asc) ----
    for (int i = tid; i < 1024; i += 512) {
        int q = i >> 8;
        int off = q * 1024 + ((q & 1) ? 768 : 0) + (i & 255);
        m2[i] = m[off];
    }
    __syncthreads();
    for (int size = 512; size <= 1024; size <<= 1) {
        for (int stride = size >> 1; stride > 0; stride >>= 1) {
            int pos = 2 * tid - (tid & (stride - 1));
            int par = pos + stride;
            bool d = ((pos & size) == 0);
            u64 a = m2[pos], bb = m2[par];
            if ((a < bb) == d) { m2[pos] = bb; m2[par] = a; }
            __syncthreads();
        }
    }

    // ---- gather top-192 boxes into LDS ----
    if (tid < 192) {
        int orig = (int)(~(unsigned)m2[tid]);
        float4 bx = boxes4[(size_t)b * N_ + orig];
        sb192[tid] = bx;
        sa192[tid] = (bx.z - bx.x) * (bx.w - bx.y);
    }
    __syncthreads();

    // ---- cmask: 192 rows x 3 words, all in LDS ----
    for (int qq = tid; qq < 576; qq += 512) {
        int r = qq / 3, w = qq - 3 * r;
        int chunk = r >> 6;
        u64 bits = 0ull;
        if (w >= chunk) {
            float4 bi = sb192[r];
            float aarea = sa192[r];
            #pragma unroll 8
            for (int t = 0; t < 64; t++) {
                float4 bj = sb192[w * 64 + t];
                float barea = sa192[w * 64 + t];
                float ix1 = fmaxf(bi.x, bj.x);
                float iy1 = fmaxf(bi.y, bj.y);
                float ix2 = fminf(bi.z, bj.z);
                float iy2 = fminf(bi.w, bj.w);
                float inter = fmaxf(ix2 - ix1, 0.0f) * fmaxf(iy2 - iy1, 0.0f);
                float uni = fmaxf(aarea + barea - inter, 1e-9f);
                if (iou_gt_half(inter, uni)) bits |= (1ull << t);
            }
            if (w == chunk) bits &= ~((2ull << (r & 63)) - 1ull);
        }
        cm[qq] = bits;
    }
    __syncthreads();

    // ---- fast greedy scan, wave 0 only, fully LDS-resident ----
    if (wave == 0) {
        u64 remv = 0ull;     // lane w owns removal word w (only 0..2 used)
        int cc = 0;
        bool fin = false;
        for (int c = 0; c < 3; c++) {
            int p = c * 64 + lane;
            u64 key = m2[p];
            float sc = mono_dec((unsigned)(key >> 32));
            u64 validb = __ballot(sc > -1e29f);
            if (validb == 0ull) { fin = true; break; }

            u64 curw = __shfl(remv, c, 64);
            u64 kept = 0ull;
            for (int t = 0; t < 64; t++) {
                u64 iv = cm[(c * 64 + t) * 3 + c];   // LDS broadcast
                u64 bit = 1ull << t;
                if (!(curw & bit) && (validb & bit)) { kept |= bit; curw |= iv; }
            }

            if ((kept >> lane) & 1ull) {
                int rank = cc + __popcll(kept & ((1ull << lane) - 1ull));
                if (rank < 128) {
                    int orig = (int)(~(unsigned)key);
                    unsigned flat = (unsigned)(cls * N_ + orig);
                    cand[bc * 128 + rank] =
                        ((u64)mono_key(sc) << 32) | (unsigned)(~flat);
                }
            }
            cc += __popcll(kept);
            if (cc >= 128) { fin = true; break; }

            if (lane < 3) {
                u64 acc = 0ull;
                for (int t = 0; t < 64; t++)
                    if ((kept >> t) & 1ull) acc |= cm[(c * 64 + t) * 3 + lane];
                remv |= acc;
            }
        }
        if (fin) {
            int filled = cc < 128 ? cc : 128;
            for (int s = lane; s < 128; s += 64)
                if (s >= filled) cand[bc * 128 + s] = 0ull;
        }
        if (lane == 0) s_fin = fin ? 1 : 0;
    }
    __syncthreads();
    if (s_fin) return;

    // ================= gated fallback (never on bench data) =================
    // m[] still holds quarter-sorted keys: finish stages 2048, 4096.
    for (int size = 2048; size <= 4096; size <<= 1) {
        for (int stride = size >> 1; stride > 0; stride >>= 1) {
            for (int t = tid; t < 2048; t += 512) {
                int pos = 2 * t - (t & (stride - 1));
                int par = pos + stride;
                bool d = ((pos & size) == 0);
                u64 a = m[pos], bb = m[par];
                if ((a < bb) == d) { m[pos] = bb; m[par] = a; }
            }
            __syncthreads();
        }
    }
    if (wave != 0) return;

    {
        u64 remv = 0ull;
        int cc = 0;
        for (int c = 0; c < 64; c++) {
            int p = c * 64 + lane;
            u64 key = m[p];
            float sc = mono_dec((unsigned)(key >> 32));
            u64 validb = __ballot(sc > -1e29f);
            if (validb == 0ull) break;

            int orig = (int)(~(unsigned)key);
            float4 bl = boxes4[(size_t)b * N_ + orig];
            sbx[lane] = bl;
            wave_fence();
            float al = (bl.z - bl.x) * (bl.w - bl.y);

            u64 intra = 0ull;
            for (int t = 0; t < 64; t++) {
                float4 bj = sbx[t];
                float ab = (bj.z - bj.x) * (bj.w - bj.y);
                float ix1 = fmaxf(bl.x, bj.x);
                float iy1 = fmaxf(bl.y, bj.y);
                float ix2 = fminf(bl.z, bj.z);
                float iy2 = fminf(bl.w, bj.w);
                float inter = fmaxf(ix2 - ix1, 0.0f) * fmaxf(iy2 - iy1, 0.0f);
                float uni = fmaxf(al + ab - inter, 1e-9f);
                if (t > lane && iou_gt_half(inter, uni)) intra |= (1ull << t);
            }
            shJ[lane] = intra;
            wave_fence();

            u64 curw = __shfl(remv, c, 64);
            u64 kept = 0ull;
            for (int t = 0; t < 64; t++) {
                u64 iv = shJ[t];
                u64 bit = 1ull << t;
                if (!(curw & bit) && (validb & bit)) { kept |= bit; curw |= iv; }
            }

            if ((kept >> lane) & 1ull) {
                int rank = cc + __popcll(kept & ((1ull << lane) - 1ull));
                if (rank < 128) {
                    unsigned flat = (unsigned)(cls * N_ + orig);
                    cand[bc * 128 + rank] =
                        ((u64)mono_key(sc) << 32) | (unsigned)(~flat);
                }
            }
            cc += __popcll(kept);
            if (cc >= 128) break;

            if (lane > c) {
                u64 accw = 0ull;
                for (int u = 0; u < 64; u++) {
                    int pj = lane * 64 + u;
                    int oj = (int)(~(unsigned)m[pj]);
                    float4 bj = boxes4[(size_t)b * N_ + oj];
                    float ab = (bj.z - bj.x) * (bj.w - bj.y);
                    bool sup = false;
                    for (int tt = 0; tt < 64; tt++) {
                        if (!((kept >> tt) & 1ull)) continue;
                        float4 br = sbx[tt];
                        float ar = (br.z - br.x) * (br.w - br.y);
                        float ix1 = fmaxf(br.x, bj.x);
                        float iy1 = fmaxf(br.y, bj.y);
                        float ix2 = fminf(br.z, bj.z);
                        float iy2 = fminf(br.w, bj.w);
                        float inter = fmaxf(ix2 - ix1, 0.0f) * fmaxf(iy2 - iy1, 0.0f);
                        float uni = fmaxf(ar + ab - inter, 1e-9f);
                        if (iou_gt_half(inter, uni)) { sup = true; break; }
                    }
                    if (sup) accw |= (1ull << u);
                }
                remv |= accw;
            }
            wave_fence();
        }
        int filled = cc < 128 ? cc : 128;
        for (int s = lane; s < 128; s += 64)
            if (s >= filled) cand[bc * 128 + s] = 0ull;
    }
}

// ---------- 2) merge 8 sorted 128-lists -> top-100, write outputs ----------
__global__ __launch_bounds__(1024) void merge_kernel(
    const u64* __restrict__ cand,
    const float* __restrict__ boxes,
    const float* __restrict__ rot,
    const float* __restrict__ trans,
    float* __restrict__ out)
{
    __shared__ u64 sk[1024];
    const int b = blockIdx.x;
    const int tid = threadIdx.x;
    const int c = tid >> 7, s = tid & 127;

    // per-class lists sorted desc; load odd classes reversed (asc)
    int src = (c & 1) ? (c * 128 + (127 - s)) : tid;
    sk[tid] = cand[(size_t)b * 1024 + src];

    for (int size = 256; size <= 1024; size <<= 1) {
        for (int stride = size >> 1; stride > 0; stride >>= 1) {
            __syncthreads();
            int partner = tid ^ stride;
            if (partner > tid) {
                bool desc = ((tid & size) == 0);
                u64 a = sk[tid], bb = sk[partner];
                if ((a < bb) == desc) { sk[tid] = bb; sk[partner] = a; }
            }
        }
    }
    __syncthreads();

    if (tid < MAXDET) {
        u64 key = sk[tid];
        float score = mono_dec((unsigned)(key >> 32));
        bool ok = score > (NEGV * 0.5f);
        unsigned flat = (~(unsigned)key) & 32767u;
        int cc = flat >> 12;
        int n = flat & (N_ - 1);

        float* obox = out;                   // 800
        float* oscr = out + 800;             // 200
        float* olab = out + 1000;            // 200
        float* orot = out + 1200;            // 600
        float* otrn = out + 1800;            // 600

        #pragma unroll
        for (int d = 0; d < 4; d++)
            obox[b * 400 + tid * 4 + d] =
                ok ? boxes[((size_t)b * N_ + n) * 4 + d] : -1.0f;
        oscr[b * MAXDET + tid] = ok ? score : -1.0f;
        olab[b * MAXDET + tid] = ok ? (float)cc : -1.0f;
        #pragma unroll
        for (int d = 0; d < 3; d++) {
            orot[b * 300 + tid * 3 + d] =
                ok ? rot[((size_t)b * N_ + n) * 3 + d] : -1.0f;
            otrn[b * 300 + tid * 3 + d] =
                ok ? trans[((size_t)b * N_ + n) * 3 + d] : -1.0f;
        }
    }
}

extern "C" void kernel_launch(void* const* d_in, const int* in_sizes, int n_in,
                              void* d_out, int out_size, void* d_ws, size_t ws_size,
                              hipStream_t stream) {
    const float* boxes = (const float*)d_in[0];
    const float* cls   = (const float*)d_in[1];
    const float* rot   = (const float*)d_in[2];
    const float* trans = (const float*)d_in[3];
    float* out = (float*)d_out;

    char* w = (char*)d_ws;
    u64* cand = (u64*)w;   w += (size_t)B_ * C_ * 128 * sizeof(u64);  // 16 KB

    mega_kernel<<<B_ * C_, 512, 0, stream>>>(cls, boxes, cand);
    merge_kernel<<<B_, 1024, 0, stream>>>(cand, boxes, rot, trans, out);
}

// Round 9
// 103.119 us; speedup vs baseline: 1.1923x; 1.1923x over previous
//
#include <hip/hip_runtime.h>
#include <hip/hip_bf16.h>
#include <stdint.h>

#define B_ 2
#define N_ 4096
#define C_ 8
#define MAXDET 100
#define SCORE_THR 0.01f
#define NMS_THR 0.5f
#define NEGV -1e30f

typedef unsigned long long u64;

// LDS index swizzle for u64 arrays: breaks the 16-element bank period
#define SW(i) ((i) + ((i) >> 4))

// ---------- helpers ----------
__device__ __forceinline__ unsigned mono_key(float f) {
    unsigned u = __float_as_uint(f);
    return (u & 0x80000000u) ? ~u : (u | 0x80000000u);
}
__device__ __forceinline__ float mono_dec(unsigned m) {
    return (m & 0x80000000u) ? __uint_as_float(m ^ 0x80000000u)
                             : __uint_as_float(~m);
}
// exact predicate: RN32(inter/uni) > 0.5  (uni > 0)
__device__ __forceinline__ bool iou_gt_half(float inter, float uni) {
    return (inter + inter - uni) > uni * 0x1p-25f;
}
// wave-synchronous LDS fence (single-wave producer/consumer)
__device__ __forceinline__ void wave_fence() {
    asm volatile("s_waitcnt lgkmcnt(0)" ::: "memory");
}

// ---------- 1) sort phase A: per-1024-chunk bitonic, alternating dirs ------
__global__ __launch_bounds__(512) void sortA_kernel(
    const float* __restrict__ cls,
    u64* __restrict__ keys)   // (B*C, N)
{
    __shared__ u64 k[1024 + 64];
    const int q = blockIdx.x;        // quarter 0..3
    const int bc = blockIdx.y;
    const int b = bc >> 3, c = bc & 7;
    const int tid = threadIdx.x;
    const bool desc = ((q & 1) == 0);

    for (int li = tid; li < 1024; li += 512) {
        int i = q * 1024 + li;
        float s = cls[((size_t)b * N_ + i) * C_ + c];
        float f = (s > SCORE_THR) ? s : NEGV;
        k[SW(li)] = ((u64)mono_key(f) << 32) | (unsigned)(~i);
    }
    __syncthreads();

    for (int size = 2; size <= 1024; size <<= 1) {
        for (int stride = size >> 1; stride > 0; stride >>= 1) {
            int t = tid;
            int pos = 2 * t - (t & (stride - 1));
            int par = pos + stride;
            bool d = ((pos & size) == 0) ? desc : !desc;
            u64 a = k[SW(pos)], bb = k[SW(par)];
            if ((a < bb) == d) { k[SW(pos)] = bb; k[SW(par)] = a; }
            __syncthreads();
        }
    }

    for (int li = tid; li < 1024; li += 512)
        keys[(size_t)bc * N_ + q * 1024 + li] = k[SW(li)];
}

// ---------- 2) fused: merge + mask + scan (+fallback) + last-block output --
__global__ __launch_bounds__(512) void fused_kernel(
    const u64* __restrict__ keys,
    const float* __restrict__ boxes,
    const float* __restrict__ rot,
    const float* __restrict__ trans,
    u64* __restrict__ cand,   // (B*C, 128)
    int* __restrict__ cnt,    // (B), zeroed by memsetAsync
    float* __restrict__ out)
{
    __shared__ u64 m[4096];          // fast: top-1024; fallback: all 4096
    __shared__ float4 sb192[192];
    __shared__ float  sa192[192];
    __shared__ u64 cm[576];          // 192 rows x 3 words
    __shared__ float4 sbx[64];       // fallback only
    __shared__ u64 shJ[64];          // fallback only
    __shared__ int s_fin;
    __shared__ int s_tick;

    const int bc = blockIdx.x;
    const int b = bc >> 3, cls = bc & 7;
    const int tid = threadIdx.x;
    const int lane = tid & 63;
    const int wave = tid >> 6;
    const size_t kbase = (size_t)bc * N_;
    const float4* boxes4 = (const float4*)boxes;

    // ---- load 4 x top-256 (quarters sorted desc/asc/desc/asc by sortA) ----
    {
        int i = tid;
        int q = i >> 8;
        int off = q * 1024 + ((q & 1) ? 768 : 0) + (i & 255);
        m[i] = keys[kbase + off];
        i = tid + 512; q = i >> 8;
        off = q * 1024 + ((q & 1) ? 768 : 0) + (i & 255);
        m[i] = keys[kbase + off];
    }
    __syncthreads();

    // ---- finish bitonic network on m[0..1023] (stages size=512,1024) ----
    for (int size = 512; size <= 1024; size <<= 1) {
        for (int stride = size >> 1; stride > 0; stride >>= 1) {
            int pos = 2 * tid - (tid & (stride - 1));
            int par = pos + stride;
            bool d = ((pos & size) == 0);
            u64 a = m[pos], bb = m[par];
            if ((a < bb) == d) { m[pos] = bb; m[par] = a; }
            __syncthreads();
        }
    }

    // ---- gather top-192 boxes into LDS ----
    if (tid < 192) {
        int orig = (int)(~(unsigned)m[tid]);
        float4 bx = boxes4[(size_t)b * N_ + orig];
        sb192[tid] = bx;
        sa192[tid] = (bx.z - bx.x) * (bx.w - bx.y);
    }
    __syncthreads();

    // ---- cmask: 192 rows x 3 words, all in LDS ----
    for (int qq = tid; qq < 576; qq += 512) {
        int r = qq / 3, w = qq - 3 * r;
        int chunk = r >> 6;
        u64 bits = 0ull;
        if (w >= chunk) {
            float4 bi = sb192[r];
            float aarea = sa192[r];
            #pragma unroll 8
            for (int t = 0; t < 64; t++) {
                float4 bj = sb192[w * 64 + t];
                float barea = sa192[w * 64 + t];
                float ix1 = fmaxf(bi.x, bj.x);
                float iy1 = fmaxf(bi.y, bj.y);
                float ix2 = fminf(bi.z, bj.z);
                float iy2 = fminf(bi.w, bj.w);
                float inter = fmaxf(ix2 - ix1, 0.0f) * fmaxf(iy2 - iy1, 0.0f);
                float uni = fmaxf(aarea + barea - inter, 1e-9f);
                if (iou_gt_half(inter, uni)) bits |= (1ull << t);
            }
            if (w == chunk) bits &= ~((2ull << (r & 63)) - 1ull);
        }
        cm[qq] = bits;
    }
    __syncthreads();

    // ---- fast greedy scan, wave 0 only, fully LDS-resident ----
    if (wave == 0) {
        u64 remv = 0ull;     // lane w owns removal word w (only 0..2 used)
        int cc = 0;
        bool fin = false;
        for (int c = 0; c < 3; c++) {
            int p = c * 64 + lane;
            u64 key = m[p];
            float sc = mono_dec((unsigned)(key >> 32));
            u64 validb = __ballot(sc > -1e29f);
            if (validb == 0ull) { fin = true; break; }

            u64 curw = __shfl(remv, c, 64);
            u64 kept = 0ull;
            for (int t = 0; t < 64; t++) {
                u64 iv = cm[(c * 64 + t) * 3 + c];   // LDS broadcast
                u64 bit = 1ull << t;
                if (!(curw & bit) && (validb & bit)) { kept |= bit; curw |= iv; }
            }

            if ((kept >> lane) & 1ull) {
                int rank = cc + __popcll(kept & ((1ull << lane) - 1ull));
                if (rank < 128) {
                    int orig = (int)(~(unsigned)key);
                    unsigned flat = (unsigned)(cls * N_ + orig);
                    cand[bc * 128 + rank] =
                        ((u64)mono_key(sc) << 32) | (unsigned)(~flat);
                }
            }
            cc += __popcll(kept);
            if (cc >= 128) { fin = true; break; }

            if (lane < 3) {
                u64 acc = 0ull;
                for (int t = 0; t < 64; t++)
                    if ((kept >> t) & 1ull) acc |= cm[(c * 64 + t) * 3 + lane];
                remv |= acc;
            }
        }
        if (fin) {
            int filled = cc < 128 ? cc : 128;
            for (int s = lane; s < 128; s += 64)
                if (s >= filled) cand[bc * 128 + s] = 0ull;
        }
        if (lane == 0) s_fin = fin ? 1 : 0;
    }
    __syncthreads();

    // ================= gated fallback (never on bench data) =================
    if (!s_fin) {
        for (int i = tid; i < 4096; i += 512) m[i] = keys[kbase + i];
        __syncthreads();
        for (int size = 2048; size <= 4096; size <<= 1) {
            for (int stride = size >> 1; stride > 0; stride >>= 1) {
                for (int t = tid; t < 2048; t += 512) {
                    int pos = 2 * t - (t & (stride - 1));
                    int par = pos + stride;
                    bool d = ((pos & size) == 0);
                    u64 a = m[pos], bb = m[par];
                    if ((a < bb) == d) { m[pos] = bb; m[par] = a; }
                }
                __syncthreads();
            }
        }
        if (wave == 0) {
            u64 remv = 0ull;
            int cc = 0;
            for (int c = 0; c < 64; c++) {
                int p = c * 64 + lane;
                u64 key = m[p];
                float sc = mono_dec((unsigned)(key >> 32));
                u64 validb = __ballot(sc > -1e29f);
                if (validb == 0ull) break;

                int orig = (int)(~(unsigned)key);
                float4 bl = boxes4[(size_t)b * N_ + orig];
                sbx[lane] = bl;
                wave_fence();
                float al = (bl.z - bl.x) * (bl.w - bl.y);

                u64 intra = 0ull;
                for (int t = 0; t < 64; t++) {
                    float4 bj = sbx[t];
                    float ab = (bj.z - bj.x) * (bj.w - bj.y);
                    float ix1 = fmaxf(bl.x, bj.x);
                    float iy1 = fmaxf(bl.y, bj.y);
                    float ix2 = fminf(bl.z, bj.z);
                    float iy2 = fminf(bl.w, bj.w);
                    float inter = fmaxf(ix2 - ix1, 0.0f) * fmaxf(iy2 - iy1, 0.0f);
                    float uni = fmaxf(al + ab - inter, 1e-9f);
                    if (t > lane && iou_gt_half(inter, uni)) intra |= (1ull << t);
                }
                shJ[lane] = intra;
                wave_fence();

                u64 curw = __shfl(remv, c, 64);
                u64 kept = 0ull;
                for (int t = 0; t < 64; t++) {
                    u64 iv = shJ[t];
                    u64 bit = 1ull << t;
                    if (!(curw & bit) && (validb & bit)) { kept |= bit; curw |= iv; }
                }

                if ((kept >> lane) & 1ull) {
                    int rank = cc + __popcll(kept & ((1ull << lane) - 1ull));
                    if (rank < 128) {
                        unsigned flat = (unsigned)(cls * N_ + orig);
                        cand[bc * 128 + rank] =
                            ((u64)mono_key(sc) << 32) | (unsigned)(~flat);
                    }
                }
                cc += __popcll(kept);
                if (cc >= 128) break;

                if (lane > c) {
                    u64 accw = 0ull;
                    for (int u = 0; u < 64; u++) {
                        int pj = lane * 64 + u;
                        int oj = (int)(~(unsigned)m[pj]);
                        float4 bj = boxes4[(size_t)b * N_ + oj];
                        float ab = (bj.z - bj.x) * (bj.w - bj.y);
                        bool sup = false;
                        for (int tt = 0; tt < 64; tt++) {
                            if (!((kept >> tt) & 1ull)) continue;
                            float4 br = sbx[tt];
                            float ar = (br.z - br.x) * (br.w - br.y);
                            float ix1 = fmaxf(br.x, bj.x);
                            float iy1 = fmaxf(br.y, bj.y);
                            float ix2 = fminf(br.z, bj.z);
                            float iy2 = fminf(br.w, bj.w);
                            float inter = fmaxf(ix2 - ix1, 0.0f) * fmaxf(iy2 - iy1, 0.0f);
                            float uni = fmaxf(ar + ab - inter, 1e-9f);
                            if (iou_gt_half(inter, uni)) { sup = true; break; }
                        }
                        if (sup) accw |= (1ull << u);
                    }
                    remv |= accw;
                }
                wave_fence();
            }
            int filled = cc < 128 ? cc : 128;
            for (int s = lane; s < 128; s += 64)
                if (s >= filled) cand[bc * 128 + s] = 0ull;
        }
    }

    // ---- ticket: last-arriving block of image b merges + writes outputs ----
    __threadfence();
    __syncthreads();
    if (tid == 0) s_tick = atomicAdd(&cnt[b], 1);
    __syncthreads();
    if (s_tick != C_ - 1) return;
    __threadfence();   // acquire: other blocks' cand writes

    // load 8 sorted 128-lists (odd classes reversed) into m[0..1023]
    for (int i = tid; i < 1024; i += 512) {
        int c2 = i >> 7, s2 = i & 127;
        int src = (c2 & 1) ? (c2 * 128 + (127 - s2)) : i;
        m[i] = cand[(size_t)b * 1024 + src];
    }
    __syncthreads();

    // bitonic merge network: 256 -> 512 -> 1024
    for (int size = 256; size <= 1024; size <<= 1) {
        for (int stride = size >> 1; stride > 0; stride >>= 1) {
            int pos = 2 * tid - (tid & (stride - 1));
            int par = pos + stride;
            bool d = ((pos & size) == 0);
            u64 a = m[pos], bb = m[par];
            if ((a < bb) == d) { m[pos] = bb; m[par] = a; }
            __syncthreads();
        }
    }

    if (tid < MAXDET) {
        u64 key = m[tid];
        float score = mono_dec((unsigned)(key >> 32));
        bool ok = score > (NEGV * 0.5f);
        unsigned flat = (~(unsigned)key) & 32767u;
        int cc2 = flat >> 12;
        int n = flat & (N_ - 1);

        float* obox = out;                   // 800
        float* oscr = out + 800;             // 200
        float* olab = out + 1000;            // 200
        float* orot = out + 1200;            // 600
        float* otrn = out + 1800;            // 600

        #pragma unroll
        for (int d = 0; d < 4; d++)
            obox[b * 400 + tid * 4 + d] =
                ok ? boxes[((size_t)b * N_ + n) * 4 + d] : -1.0f;
        oscr[b * MAXDET + tid] = ok ? score : -1.0f;
        olab[b * MAXDET + tid] = ok ? (float)cc2 : -1.0f;
        #pragma unroll
        for (int d = 0; d < 3; d++) {
            orot[b * 300 + tid * 3 + d] =
                ok ? rot[((size_t)b * N_ + n) * 3 + d] : -1.0f;
            otrn[b * 300 + tid * 3 + d] =
                ok ? trans[((size_t)b * N_ + n) * 3 + d] : -1.0f;
        }
    }
}

extern "C" void kernel_launch(void* const* d_in, const int* in_sizes, int n_in,
                              void* d_out, int out_size, void* d_ws, size_t ws_size,
                              hipStream_t stream) {
    const float* boxes = (const float*)d_in[0];
    const float* cls   = (const float*)d_in[1];
    const float* rot   = (const float*)d_in[2];
    const float* trans = (const float*)d_in[3];
    float* out = (float*)d_out;

    char* w = (char*)d_ws;
    u64* keys = (u64*)w;   w += (size_t)B_ * C_ * N_ * sizeof(u64);   // 512 KB
    u64* cand = (u64*)w;   w += (size_t)B_ * C_ * 128 * sizeof(u64);  // 16 KB
    int* cnt  = (int*)w;   w += B_ * sizeof(int);

    hipMemsetAsync(cnt, 0, B_ * sizeof(int), stream);
    sortA_kernel<<<dim3(4, B_ * C_), 512, 0, stream>>>(cls, keys);
    fused_kernel<<<B_ * C_, 512, 0, stream>>>(keys, boxes, rot, trans,
                                              cand, cnt, out);
}

// Round 10
// 100.121 us; speedup vs baseline: 1.2280x; 1.0299x over previous
//
#include <hip/hip_runtime.h>
#include <hip/hip_bf16.h>
#include <stdint.h>

#define B_ 2
#define N_ 4096
#define C_ 8
#define MAXDET 100
#define SCORE_THR 0.01f
#define NMS_THR 0.5f
#define NEGV -1e30f

typedef unsigned long long u64;

// LDS index swizzle for u64 arrays: breaks the 16-element bank period
#define SW(i) ((i) + ((i) >> 4))

// ---------- helpers ----------
__device__ __forceinline__ unsigned mono_key(float f) {
    unsigned u = __float_as_uint(f);
    return (u & 0x80000000u) ? ~u : (u | 0x80000000u);
}
__device__ __forceinline__ float mono_dec(unsigned m) {
    return (m & 0x80000000u) ? __uint_as_float(m ^ 0x80000000u)
                             : __uint_as_float(~m);
}
// exact predicate: RN32(inter/uni) > 0.5  (uni > 0)
__device__ __forceinline__ bool iou_gt_half(float inter, float uni) {
    return (inter + inter - uni) > uni * 0x1p-25f;
}
// wave-synchronous LDS fence (single-wave producer/consumer, no s_barrier)
__device__ __forceinline__ void wave_fence() {
    asm volatile("s_waitcnt lgkmcnt(0)" ::: "memory");
}

// ---------- 1) sort phase A: per-1024-chunk bitonic, alternating dirs ------
__global__ __launch_bounds__(512) void sortA_kernel(
    const float* __restrict__ cls,
    u64* __restrict__ keys)   // (B*C, N)
{
    __shared__ u64 k[1024 + 64];
    const int q = blockIdx.x;        // quarter 0..3
    const int bc = blockIdx.y;
    const int b = bc >> 3, c = bc & 7;
    const int tid = threadIdx.x;
    const bool desc = ((q & 1) == 0);

    for (int li = tid; li < 1024; li += 512) {
        int i = q * 1024 + li;
        float s = cls[((size_t)b * N_ + i) * C_ + c];
        float f = (s > SCORE_THR) ? s : NEGV;
        k[SW(li)] = ((u64)mono_key(f) << 32) | (unsigned)(~i);
    }
    __syncthreads();

    for (int size = 2; size <= 1024; size <<= 1) {
        for (int stride = size >> 1; stride > 0; stride >>= 1) {
            int t = tid;
            int pos = 2 * t - (t & (stride - 1));
            int par = pos + stride;
            bool d = ((pos & size) == 0) ? desc : !desc;
            u64 a = k[SW(pos)], bb = k[SW(par)];
            if ((a < bb) == d) { k[SW(pos)] = bb; k[SW(par)] = a; }
            __syncthreads();
        }
    }

    for (int li = tid; li < 1024; li += 512)
        keys[(size_t)bc * N_ + q * 1024 + li] = k[SW(li)];
}

// ---------- 2) fused: top-1024 merge + mask + greedy scan (+gated fallback) -
__global__ __launch_bounds__(512) void fused_kernel(
    const u64* __restrict__ keys,
    const float* __restrict__ boxes,
    u64* __restrict__ cand)   // (B*C, 128)
{
    __shared__ u64 m[4096];          // fast: top-1024; fallback: all 4096
    __shared__ float4 sb192[192];
    __shared__ float  sa192[192];
    __shared__ u64 cm[576];          // 192 rows x 3 words
    __shared__ float4 sbx[64];       // fallback only
    __shared__ u64 shJ[64];          // fallback only
    __shared__ int s_fin;

    const int bc = blockIdx.x;
    const int b = bc >> 3, cls = bc & 7;
    const int tid = threadIdx.x;
    const int lane = tid & 63;
    const int wave = tid >> 6;
    const size_t kbase = (size_t)bc * N_;
    const float4* boxes4 = (const float4*)boxes;

    // ---- load 4 x top-256 (quarters sorted desc/asc/desc/asc by sortA) ----
    {
        int i = tid;
        int q = i >> 8;
        int off = q * 1024 + ((q & 1) ? 768 : 0) + (i & 255);
        m[i] = keys[kbase + off];
        i = tid + 512; q = i >> 8;
        off = q * 1024 + ((q & 1) ? 768 : 0) + (i & 255);
        m[i] = keys[kbase + off];
    }
    __syncthreads();

    // ---- finish bitonic network on m[0..1023] (stages size=512,1024) ----
    for (int size = 512; size <= 1024; size <<= 1) {
        for (int stride = size >> 1; stride > 0; stride >>= 1) {
            int pos = 2 * tid - (tid & (stride - 1));
            int par = pos + stride;
            bool d = ((pos & size) == 0);
            u64 a = m[pos], bb = m[par];
            if ((a < bb) == d) { m[pos] = bb; m[par] = a; }
            __syncthreads();
        }
    }

    // ---- gather top-192 boxes into LDS ----
    if (tid < 192) {
        int orig = (int)(~(unsigned)m[tid]);
        float4 bx = boxes4[(size_t)b * N_ + orig];
        sb192[tid] = bx;
        sa192[tid] = (bx.z - bx.x) * (bx.w - bx.y);
    }
    __syncthreads();

    // ---- cmask: 192 rows x 3 words, all in LDS ----
    for (int qq = tid; qq < 576; qq += 512) {
        int r = qq / 3, w = qq - 3 * r;
        int chunk = r >> 6;
        u64 bits = 0ull;
        if (w >= chunk) {
            float4 bi = sb192[r];
            float aarea = sa192[r];
            #pragma unroll 8
            for (int t = 0; t < 64; t++) {
                float4 bj = sb192[w * 64 + t];
                float barea = sa192[w * 64 + t];
                float ix1 = fmaxf(bi.x, bj.x);
                float iy1 = fmaxf(bi.y, bj.y);
                float ix2 = fminf(bi.z, bj.z);
                float iy2 = fminf(bi.w, bj.w);
                float inter = fmaxf(ix2 - ix1, 0.0f) * fmaxf(iy2 - iy1, 0.0f);
                float uni = fmaxf(aarea + barea - inter, 1e-9f);
                if (iou_gt_half(inter, uni)) bits |= (1ull << t);
            }
            if (w == chunk) bits &= ~((2ull << (r & 63)) - 1ull);
        }
        cm[qq] = bits;
    }
    __syncthreads();

    // ---- fast greedy scan, wave 0 only, fully LDS-resident ----
    if (wave == 0) {
        u64 remv = 0ull;     // lane w owns removal word w (only 0..2 used)
        int cc = 0;
        bool fin = false;
        for (int c = 0; c < 3; c++) {
            int p = c * 64 + lane;
            u64 key = m[p];
            float sc = mono_dec((unsigned)(key >> 32));
            u64 validb = __ballot(sc > -1e29f);
            if (validb == 0ull) { fin = true; break; }

            u64 curw = __shfl(remv, c, 64);
            u64 kept = 0ull;
            for (int t = 0; t < 64; t++) {
                u64 iv = cm[(c * 64 + t) * 3 + c];   // LDS broadcast
                u64 bit = 1ull << t;
                if (!(curw & bit) && (validb & bit)) { kept |= bit; curw |= iv; }
            }

            if ((kept >> lane) & 1ull) {
                int rank = cc + __popcll(kept & ((1ull << lane) - 1ull));
                if (rank < 128) {
                    int orig = (int)(~(unsigned)key);
                    unsigned flat = (unsigned)(cls * N_ + orig);
                    cand[bc * 128 + rank] =
                        ((u64)mono_key(sc) << 32) | (unsigned)(~flat);
                }
            }
            cc += __popcll(kept);
            if (cc >= 128) { fin = true; break; }

            if (lane < 3) {
                u64 acc = 0ull;
                for (int t = 0; t < 64; t++)
                    if ((kept >> t) & 1ull) acc |= cm[(c * 64 + t) * 3 + lane];
                remv |= acc;
            }
        }
        if (fin) {
            int filled = cc < 128 ? cc : 128;
            for (int s = lane; s < 128; s += 64)
                if (s >= filled) cand[bc * 128 + s] = 0ull;
        }
        if (lane == 0) s_fin = fin ? 1 : 0;
    }
    __syncthreads();
    if (s_fin) return;

    // ================= gated fallback (never on bench data) =================
    // finish the full 4096 sort in LDS, then wave-0 on-the-fly NMS.
    for (int i = tid; i < 4096; i += 512) m[i] = keys[kbase + i];
    __syncthreads();
    for (int size = 2048; size <= 4096; size <<= 1) {
        for (int stride = size >> 1; stride > 0; stride >>= 1) {
            for (int t = tid; t < 2048; t += 512) {
                int pos = 2 * t - (t & (stride - 1));
                int par = pos + stride;
                bool d = ((pos & size) == 0);
                u64 a = m[pos], bb = m[par];
                if ((a < bb) == d) { m[pos] = bb; m[par] = a; }
            }
            __syncthreads();
        }
    }
    if (wave != 0) return;

    {
        u64 remv = 0ull;
        int cc = 0;
        for (int c = 0; c < 64; c++) {
            int p = c * 64 + lane;
            u64 key = m[p];
            float sc = mono_dec((unsigned)(key >> 32));
            u64 validb = __ballot(sc > -1e29f);
            if (validb == 0ull) break;

            int orig = (int)(~(unsigned)key);
            float4 bl = boxes4[(size_t)b * N_ + orig];
            sbx[lane] = bl;
            wave_fence();
            float al = (bl.z - bl.x) * (bl.w - bl.y);

            u64 intra = 0ull;
            for (int t = 0; t < 64; t++) {
                float4 bj = sbx[t];
                float ab = (bj.z - bj.x) * (bj.w - bj.y);
                float ix1 = fmaxf(bl.x, bj.x);
                float iy1 = fmaxf(bl.y, bj.y);
                float ix2 = fminf(bl.z, bj.z);
                float iy2 = fminf(bl.w, bj.w);
                float inter = fmaxf(ix2 - ix1, 0.0f) * fmaxf(iy2 - iy1, 0.0f);
                float uni = fmaxf(al + ab - inter, 1e-9f);
                if (t > lane && iou_gt_half(inter, uni)) intra |= (1ull << t);
            }
            shJ[lane] = intra;
            wave_fence();

            u64 curw = __shfl(remv, c, 64);
            u64 kept = 0ull;
            for (int t = 0; t < 64; t++) {
                u64 iv = shJ[t];
                u64 bit = 1ull << t;
                if (!(curw & bit) && (validb & bit)) { kept |= bit; curw |= iv; }
            }

            if ((kept >> lane) & 1ull) {
                int rank = cc + __popcll(kept & ((1ull << lane) - 1ull));
                if (rank < 128) {
                    unsigned flat = (unsigned)(cls * N_ + orig);
                    cand[bc * 128 + rank] =
                        ((u64)mono_key(sc) << 32) | (unsigned)(~flat);
                }
            }
            cc += __popcll(kept);
            if (cc >= 128) break;

            if (lane > c) {
                u64 accw = 0ull;
                for (int u = 0; u < 64; u++) {
                    int pj = lane * 64 + u;
                    int oj = (int)(~(unsigned)m[pj]);
                    float4 bj = boxes4[(size_t)b * N_ + oj];
                    float ab = (bj.z - bj.x) * (bj.w - bj.y);
                    bool sup = false;
                    for (int tt = 0; tt < 64; tt++) {
                        if (!((kept >> tt) & 1ull)) continue;
                        float4 br = sbx[tt];
                        float ar = (br.z - br.x) * (br.w - br.y);
                        float ix1 = fmaxf(br.x, bj.x);
                        float iy1 = fmaxf(br.y, bj.y);
                        float ix2 = fminf(br.z, bj.z);
                        float iy2 = fminf(br.w, bj.w);
                        float inter = fmaxf(ix2 - ix1, 0.0f) * fmaxf(iy2 - iy1, 0.0f);
                        float uni = fmaxf(ar + ab - inter, 1e-9f);
                        if (iou_gt_half(inter, uni)) { sup = true; break; }
                    }
                    if (sup) accw |= (1ull << u);
                }
                remv |= accw;
            }
            wave_fence();
        }
        int filled = cc < 128 ? cc : 128;
        for (int s = lane; s < 128; s += 64)
            if (s >= filled) cand[bc * 128 + s] = 0ull;
    }
}

// ---------- 3) merge 8 sorted 128-lists -> top-100, write outputs ----------
__global__ __launch_bounds__(1024) void merge_kernel(
    const u64* __restrict__ cand,
    const float* __restrict__ boxes,
    const float* __restrict__ rot,
    const float* __restrict__ trans,
    float* __restrict__ out)
{
    __shared__ u64 sk[1024];
    const int b = blockIdx.x;
    const int tid = threadIdx.x;
    const int c = tid >> 7, s = tid & 127;

    // per-class lists sorted desc; load odd classes reversed (asc)
    int src = (c & 1) ? (c * 128 + (127 - s)) : tid;
    sk[tid] = cand[(size_t)b * 1024 + src];

    for (int size = 256; size <= 1024; size <<= 1) {
        for (int stride = size >> 1; stride > 0; stride >>= 1) {
            __syncthreads();
            int partner = tid ^ stride;
            if (partner > tid) {
                bool desc = ((tid & size) == 0);
                u64 a = sk[tid], bb = sk[partner];
                if ((a < bb) == desc) { sk[tid] = bb; sk[partner] = a; }
            }
        }
    }
    __syncthreads();

    if (tid < MAXDET) {
        u64 key = sk[tid];
        float score = mono_dec((unsigned)(key >> 32));
        bool ok = score > (NEGV * 0.5f);
        unsigned flat = (~(unsigned)key) & 32767u;
        int cc = flat >> 12;
        int n = flat & (N_ - 1);

        float* obox = out;                   // 800
        float* oscr = out + 800;             // 200
        float* olab = out + 1000;            // 200
        float* orot = out + 1200;            // 600
        float* otrn = out + 1800;            // 600

        #pragma unroll
        for (int d = 0; d < 4; d++)
            obox[b * 400 + tid * 4 + d] =
                ok ? boxes[((size_t)b * N_ + n) * 4 + d] : -1.0f;
        oscr[b * MAXDET + tid] = ok ? score : -1.0f;
        olab[b * MAXDET + tid] = ok ? (float)cc : -1.0f;
        #pragma unroll
        for (int d = 0; d < 3; d++) {
            orot[b * 300 + tid * 3 + d] =
                ok ? rot[((size_t)b * N_ + n) * 3 + d] : -1.0f;
            otrn[b * 300 + tid * 3 + d] =
                ok ? trans[((size_t)b * N_ + n) * 3 + d] : -1.0f;
        }
    }
}

extern "C" void kernel_launch(void* const* d_in, const int* in_sizes, int n_in,
                              void* d_out, int out_size, void* d_ws, size_t ws_size,
                              hipStream_t stream) {
    const float* boxes = (const float*)d_in[0];
    const float* cls   = (const float*)d_in[1];
    const float* rot   = (const float*)d_in[2];
    const float* trans = (const float*)d_in[3];
    float* out = (float*)d_out;

    char* w = (char*)d_ws;
    u64* keys = (u64*)w;   w += (size_t)B_ * C_ * N_ * sizeof(u64);   // 512 KB
    u64* cand = (u64*)w;   w += (size_t)B_ * C_ * 128 * sizeof(u64);  // 16 KB

    sortA_kernel<<<dim3(4, B_ * C_), 512, 0, stream>>>(cls, keys);
    fused_kernel<<<B_ * C_, 512, 0, stream>>>(keys, boxes, cand);
    merge_kernel<<<B_, 1024, 0, stream>>>(cand, boxes, rot, trans, out);
}